// Round 6
// baseline (3605.428 us; speedup 1.0000x reference)
//
#include <hip/hip_runtime.h>
#include <hip/hip_bf16.h>
#include <stdint.h>

typedef __attribute__((ext_vector_type(8))) __bf16 bf16x8;
typedef __attribute__((ext_vector_type(4))) float  floatx4;

#define T_STEPS 256
#define BATCH   128
#define HID     512

__device__ __forceinline__ float sigmoidf_(float x) { return 1.f / (1.f + __expf(-x)); }
__device__ __forceinline__ float tanhf_(float y) {
  float e = __expf(-2.f * fabsf(y));
  return copysignf((1.f - e) / (1.f + e), y);
}

// fp32 [b][t][256] -> bf16 time-major [t][b][256], 8 elems/thread
__global__ __launch_bounds__(256) void cvt_bf16_tmajor(const float* __restrict__ in,
                                                       __bf16* __restrict__ out) {
  int id = blockIdx.x * 256 + threadIdx.x;     // [0, 1048576)
  int i8 = id & 31;
  int bt = id >> 5;
  int t  = bt & 255;
  int b  = bt >> 8;
  const floatx4* p = (const floatx4*)(in + ((size_t)(b * 256 + t) * 256 + i8 * 8));
  floatx4 a = p[0], v = p[1];
  bf16x8 o;
  o[0] = (__bf16)a[0]; o[1] = (__bf16)a[1]; o[2] = (__bf16)a[2]; o[3] = (__bf16)a[3];
  o[4] = (__bf16)v[0]; o[5] = (__bf16)v[1]; o[6] = (__bf16)v[2]; o[7] = (__bf16)v[3];
  *(bf16x8*)(out + ((size_t)(t * 128 + b) * 256 + i8 * 8)) = o;
}

// Persistent GRU layer scan.
// Grid = 128 blocks = 2 batch-groups (64 rows each) x 64 hidden-groups (8 cols each).
// h exchange: FRESH time-major slab per step (slab t = h after step t, [128][512]).
// Addresses are never reused, so consumer L2s can never hold a stale copy:
//   producer: packed 4B relaxed AGENT atomic stores (write-through to coherence
//             point) -> s_waitcnt vmcnt(0) -> __syncthreads -> plain relaxed
//             atomic store of (t+1) into this producer's PRIVATE 128B flag line.
//   consumer: ONLY WAVE 0 polls (lane l watches producer l's line; one 64-lane
//             gather over 64 distinct lines per spin), paced by s_sleep ->
//             __syncthreads releases the other waves -> PLAIN cached b128 h
//             loads (first toucher per XCD misses to L3, rest hit L2).
// Sync latency hidden by computing next step's x-phase between post and poll.
__global__ __launch_bounds__(256) void gru_scan(
    const __bf16* __restrict__ xLo, const __bf16* __restrict__ xHi, int Kin,
    const float* __restrict__ Wih, const float* __restrict__ Whh,
    const float* __restrict__ bih, const float* __restrict__ bhh,
    __bf16* __restrict__ hLo, __bf16* __restrict__ hHi,  // 128 slabs each
    int* flags)                  // [2 bg][64 g][32] (128B-padded), zero-init
{
  const int tid = threadIdx.x;
  const int g   = blockIdx.x & 63;     // hidden group: cols [8g, 8g+8)
  const int bg  = blockIdx.x >> 6;     // batch group: rows [64bg, 64bg+64)
  const int w   = tid >> 6;            // wave 0..3, one 16-row m-tile each
  const int l   = tid & 63;
  const int c   = l & 15;
  const int q   = l >> 4;
  const int KTx = Kin >> 5;            // x-phase k-tiles (8 or 16)
  const int KT  = KTx + 16;            // + h-phase k-tiles
  const int rowbase = bg * 64 + w * 16;
  const int jj  = g * 8 + c;           // owned hidden col (lanes c<8)

  __shared__ __bf16 ldsW[2 * 32 * 64 * 8];   // 64 KiB max (KT<=32)

  auto hslab = [&](int t) -> __bf16* {
    return (t < 128 ? hLo : hHi) + (size_t)(t & 127) * (BATCH * HID);
  };
  auto xslab = [&](int t) -> const __bf16* {
    return (t < 128 ? xLo : xHi) + (size_t)(t & 127) * (size_t)(BATCH * Kin);
  };

  // ---- stage W slice (fp32 -> bf16) into frag-order LDS
  // tile0 cols: [r0..7 | z0..7], tile1 cols: [n0..7 | zeros]
  for (int cid = tid; cid < 2 * KT * 64; cid += 256) {
    int nt = cid / (KT * 64);
    int r1 = cid - nt * (KT * 64);
    int kt = r1 >> 6;
    int ll = r1 & 63;
    int cc = ll & 15, qq = ll >> 4;
    int k  = kt * 32 + qq * 8;
    int grow;
    if (nt == 0) grow = (cc < 8) ? (g * 8 + cc) : (512 + g * 8 + (cc - 8));
    else         grow = (cc < 8) ? (1024 + g * 8 + cc) : -1;
    bf16x8 v;
    if (grow >= 0) {
      const float* src = (k < Kin) ? (Wih + (size_t)grow * Kin + k)
                                   : (Whh + (size_t)grow * HID + (k - Kin));
      #pragma unroll
      for (int j = 0; j < 8; ++j) v[j] = (__bf16)src[j];
    } else {
      #pragma unroll
      for (int j = 0; j < 8; ++j) v[j] = (__bf16)0.f;
    }
    *(bf16x8*)&ldsW[((size_t)(nt * KT + kt) * 64 + ll) * 8] = v;
  }
  __syncthreads();

  // ---- hoist the h-part W fragments (compiler may keep in regs or re-read LDS)
  bf16x8 WH[16][2];
  #pragma unroll
  for (int kt = 0; kt < 16; ++kt) {
    WH[kt][0] = *(const bf16x8*)&ldsW[((size_t)(0 * KT + KTx + kt) * 64 + l) * 8];
    WH[kt][1] = *(const bf16x8*)&ldsW[((size_t)(1 * KT + KTx + kt) * 64 + l) * 8];
  }

  // ---- per-lane biases (constant over steps)
  float bias0, bias_nx, bias_nh;
  if (c < 8) {
    bias0   = bih[jj] + bhh[jj];          // r-gate
    bias_nx = bih[1024 + jj];
    bias_nh = bhh[1024 + jj];
  } else {
    int j2 = g * 8 + (c - 8);
    bias0   = bih[512 + j2] + bhh[512 + j2];  // z-gate (consumed via shfl)
    bias_nx = 0.f; bias_nh = 0.f;
  }

  floatx4 accA[2], accB[2];
  const floatx4 zero4 = {0.f, 0.f, 0.f, 0.f};
  float hprev[4] = {0.f, 0.f, 0.f, 0.f};   // own h (lanes c<8), t=0 state

  auto phaseX = [&](int t) {
    accA[0] = zero4; accA[1] = zero4;
    const __bf16* xp = xslab(t) + (size_t)(rowbase + c) * Kin + q * 8;
    for (int kt = 0; kt < KTx; ++kt) {
      bf16x8 b0 = *(const bf16x8*)&ldsW[((size_t)(0 * KT + kt) * 64 + l) * 8];
      bf16x8 b1 = *(const bf16x8*)&ldsW[((size_t)(1 * KT + kt) * 64 + l) * 8];
      bf16x8 a = *(const bf16x8*)(xp + kt * 32);
      accA[0] = __builtin_amdgcn_mfma_f32_16x16x32_bf16(a, b0, accA[0], 0, 0, 0);
      accA[1] = __builtin_amdgcn_mfma_f32_16x16x32_bf16(a, b1, accA[1], 0, 0, 0);
    }
  };

  phaseX(0);

  int* fpost = flags + (bg * 64 + g) * 32;   // this block's private flag line
  int* fbase = flags + (bg * 64 + l) * 32;   // lane l watches producer l (wave 0)

  for (int t = 0; t < T_STEPS; ++t) {
    // ---- phase H: accB = h_{t-1} @ Whh_slice^T  (plain cached b128 loads,
    //      slab t-1 is fresh-addressed so no staleness is possible)
    accB[0] = zero4; accB[1] = zero4;
    if (t > 0) {
      const __bf16* hA = hslab(t - 1) + (size_t)(rowbase + c) * HID + q * 8;
      bf16x8 hfrag[16];
      #pragma unroll
      for (int kt = 0; kt < 16; ++kt)
        hfrag[kt] = *(const bf16x8*)(hA + kt * 32);
      #pragma unroll
      for (int kt = 0; kt < 16; ++kt) {
        accB[0] = __builtin_amdgcn_mfma_f32_16x16x32_bf16(hfrag[kt], WH[kt][0], accB[0], 0, 0, 0);
        accB[1] = __builtin_amdgcn_mfma_f32_16x16x32_bf16(hfrag[kt], WH[kt][1], accB[1], 0, 0, 0);
      }
    }

    // ---- epilogue: gates + h update; packed-pair agent stores (write-through)
    __bf16* hs = hslab(t);
    #pragma unroll
    for (int rg = 0; rg < 4; ++rg) {
      float pre0 = accA[0][rg] + accB[0][rg] + bias0;
      float zs = __shfl(pre0, (l & 48) | ((c + 8) & 15), 64);  // z from lane c+8
      float r  = sigmoidf_(pre0);
      float z  = sigmoidf_(zs);
      float nn = tanhf_(accA[1][rg] + bias_nx + r * (accB[1][rg] + bias_nh));
      float hnew = (1.f - z) * nn + z * hprev[rg];
      hprev[rg] = hnew;
      unsigned short us = __builtin_bit_cast(unsigned short, (__bf16)hnew);
      int po = __shfl_xor((int)us, 1, 64);                     // partner col's bits
      if (c < 8 && (c & 1) == 0) {
        uint32_t v = (uint32_t)us | ((uint32_t)po << 16);
        int row = rowbase + q * 4 + rg;
        __hip_atomic_store((uint32_t*)(hs + (size_t)row * HID + jj), v,
                           __ATOMIC_RELAXED, __HIP_MEMORY_SCOPE_AGENT);
      }
    }

    if (t + 1 < T_STEPS) {
      // drain our h stores to the coherence point (per wave), barrier so ALL
      // waves' stores are drained, then post our private flag line (plain
      // store, no RMW -> no same-line serialization)
      asm volatile("s_waitcnt vmcnt(0)" ::: "memory");
      __syncthreads();
      if (tid == 0)
        __hip_atomic_store(fpost, t + 1, __ATOMIC_RELAXED, __HIP_MEMORY_SCOPE_AGENT);

      phaseX(t + 1);            // no h dependency -> hides flag flight

      if (w == 0) {             // ONLY wave 0 polls; s_sleep pacing
        const int target = t + 1;
        while (1) {
          int v = __hip_atomic_load(fbase, __ATOMIC_RELAXED, __HIP_MEMORY_SCOPE_AGENT);
          if (__all(v >= target)) break;
          __builtin_amdgcn_s_sleep(2);
        }
      }
      __syncthreads();          // release waves 1-3; orders h loads after poll
    }
  }
}

// yhat[b][o] = h1_last[b][:] . Wout[o][:] + bout[o]
__global__ __launch_bounds__(64) void outproj(const __bf16* __restrict__ h1,
                                              const float* __restrict__ Wout,
                                              const float* __restrict__ bout,
                                              float* __restrict__ out) {
  int b = blockIdx.x, o = threadIdx.x;
  const __bf16* hr = h1 + (size_t)b * HID;
  const float*  wr = Wout + (size_t)o * HID;
  float acc = bout[o];
  for (int k = 0; k < HID; k += 8) {
    bf16x8 h8 = *(const bf16x8*)(hr + k);
    #pragma unroll
    for (int j = 0; j < 8; ++j) acc += (float)h8[j] * wr[k + j];
  }
  out[b * 64 + o] = acc;
}

extern "C" void kernel_launch(void* const* d_in, const int* in_sizes, int n_in,
                              void* d_out, int out_size, void* d_ws, size_t ws_size,
                              hipStream_t stream) {
  const float* x    = (const float*)d_in[0];
  const float* Wih0 = (const float*)d_in[1];
  const float* Whh0 = (const float*)d_in[2];
  const float* bih0 = (const float*)d_in[3];
  const float* bhh0 = (const float*)d_in[4];
  const float* Wih1 = (const float*)d_in[5];
  const float* Whh1 = (const float*)d_in[6];
  const float* bih1 = (const float*)d_in[7];
  const float* bhh1 = (const float*)d_in[8];
  const float* Wout = (const float*)d_in[9];
  const float* bout = (const float*)d_in[10];

  char* ws = (char*)d_ws;
  // ws layout (bytes):
  //   [0, 16 MiB)       xbf: x as bf16 time-major [t][b][256]  (256 slabs x 64 KB)
  //                     ... later OVERLAID by h1seq slabs [0,128) (layer 0 done)
  //   [16 MiB, 48 MiB)  h0seq: 256 slabs x 128 KB ([t][b][512])
  //   [48 MiB, 64 MiB)  h1seq slabs [128, 256)
  //   [64 MiB, +32 KiB) flags: layer0 [2][64][32] ints, layer1 same
  __bf16* xbf  = (__bf16*)(ws);
  __bf16* h0lo = (__bf16*)(ws + (16u << 20));
  __bf16* h0hi = (__bf16*)(ws + (32u << 20));
  __bf16* h1lo = (__bf16*)(ws);                 // overlay on dead xbf
  __bf16* h1hi = (__bf16*)(ws + (48u << 20));
  int*    fl0  = (int*)(ws + (64u << 20));
  int*    fl1  = fl0 + 2 * 64 * 32;

  // zero the flag lines (ws is poisoned before every launch)
  hipMemsetAsync(fl0, 0, 2 * 2 * 64 * 32 * 4, stream);

  // x fp32 -> bf16 time-major (1,048,576 threads x 8 elems)
  cvt_bf16_tmajor<<<4096, 256, 0, stream>>>(x, xbf);

  const __bf16* x0hi = xbf + (size_t)128 * 128 * 256;   // slab 128 of x

  // layer 0: x slabs = xbf (64 KB each), h slabs = h0seq
  gru_scan<<<128, 256, 0, stream>>>(xbf, x0hi, 256,
                                    Wih0, Whh0, bih0, bhh0, h0lo, h0hi, fl0);
  // layer 1: x slabs = h0seq (128 KB each), h slabs = h1seq (overlaid)
  gru_scan<<<128, 256, 0, stream>>>(h0lo, h0hi, HID,
                                    Wih1, Whh1, bih1, bhh1, h1lo, h1hi, fl1);

  // final h1 = slab 255 = h1hi + 127 slabs
  outproj<<<128, 64, 0, stream>>>(h1hi + (size_t)127 * BATCH * HID,
                                  Wout, bout, (float*)d_out);
}

// Round 8
// 1732.500 us; speedup vs baseline: 2.0811x; 2.0811x over previous
//
#include <hip/hip_runtime.h>
#include <hip/hip_bf16.h>
#include <stdint.h>

typedef __attribute__((ext_vector_type(8))) __bf16 bf16x8;
typedef __attribute__((ext_vector_type(4))) float  floatx4;

#define T_STEPS 256
#define BATCH   128
#define HID     512

__device__ __forceinline__ float sigmoidf_(float x) { return 1.f / (1.f + __expf(-x)); }
__device__ __forceinline__ float tanhf_(float y) {
  float e = __expf(-2.f * fabsf(y));
  return copysignf((1.f - e) / (1.f + e), y);
}

// poll a per-lane flag line until all 64 watched values >= target.
template <int SLP>
__device__ __forceinline__ void pollline_(const int* base, int target) {
  while (1) {
    int v = __hip_atomic_load(base, __ATOMIC_RELAXED, __HIP_MEMORY_SCOPE_AGENT);
    if (__all(v >= target)) break;
    __builtin_amdgcn_s_sleep(SLP);
  }
  asm volatile("" ::: "memory");
}

// Fused 2-layer persistent GRU scan, software-pipelined across layers.
// Grid = 256 blocks: [layer(2)][bg(2)][g(64)].
//   layer L, bg, g: owns hidden cols [8g,8g+8) for batch rows [64bg,64bg+64).
// h exchange: FRESH time-major slab per step (slab t = h after step t).
// Per-step protocol (per layer-ring, unchanged from round 4):
//   producer: packed 4B relaxed AGENT atomic stores -> vmcnt(0) -> barrier ->
//             plain relaxed store of t+1 to private 128B flag line.
//   consumer: poll 64 flag lines (lane l watches line l, all waves, s_sleep
//             paced) -> plain cached b128 h loads (fresh addresses => no
//             staleness possible; first toucher/XCD misses to L3, rest hit L2).
// Cross-layer: layer-1's phaseX(t) reads h0 slab t, gated on layer-0 flags
//   >= t+1. In steady state layer 0 runs ~1 step ahead so the gate is
//   usually already satisfied -> both layers advance concurrently.
// Layer-0 phaseX reads x directly as fp32 [b][t][256] (cvt folded in, done
// inside the hidden gap between flag post and own-ring poll).
__global__ __launch_bounds__(256) void gru_fused(
    const float* __restrict__ x,                              // [128][256][256] fp32
    const float* __restrict__ Wih0, const float* __restrict__ Whh0,
    const float* __restrict__ bih0, const float* __restrict__ bhh0,
    const float* __restrict__ Wih1, const float* __restrict__ Whh1,
    const float* __restrict__ bih1, const float* __restrict__ bhh1,
    __bf16* __restrict__ h0base,                              // [256][128][512]
    __bf16* __restrict__ h1base,                              // [256][128][512]
    int* __restrict__ fl)                                     // [2][2][64][32]
{
  const int tid   = threadIdx.x;
  const int layer = blockIdx.x >> 7;
  const int bg    = (blockIdx.x >> 6) & 1;
  const int g     = blockIdx.x & 63;
  const int w = tid >> 6, l = tid & 63, c = l & 15, q = l >> 4;
  const int Kin = layer ? HID : 256;
  const int KTx = Kin >> 5;            // 8 or 16
  const int KT  = KTx + 16;
  const int rowbase = bg * 64 + w * 16;
  const int jj  = g * 8 + c;

  const float* Wih = layer ? Wih1 : Wih0;
  const float* Whh = layer ? Whh1 : Whh0;
  const float* bih = layer ? bih1 : bih0;
  const float* bhh = layer ? bhh1 : bhh0;
  __bf16* hbase = layer ? h1base : h0base;

  __shared__ __bf16 ldsW[2 * 32 * 64 * 8];   // 64 KiB max (KT<=32)

  // ---- stage W slice (fp32 -> bf16) into frag-order LDS
  // tile0 cols: [r0..7 | z0..7], tile1 cols: [n0..7 | zeros]
  for (int cid = tid; cid < 2 * KT * 64; cid += 256) {
    int nt = cid / (KT * 64);
    int r1 = cid - nt * (KT * 64);
    int kt = r1 >> 6;
    int ll = r1 & 63;
    int cc = ll & 15, qq = ll >> 4;
    int k  = kt * 32 + qq * 8;
    int grow;
    if (nt == 0) grow = (cc < 8) ? (g * 8 + cc) : (512 + g * 8 + (cc - 8));
    else         grow = (cc < 8) ? (1024 + g * 8 + cc) : -1;
    bf16x8 v;
    if (grow >= 0) {
      const float* src = (k < Kin) ? (Wih + (size_t)grow * Kin + k)
                                   : (Whh + (size_t)grow * HID + (k - Kin));
      #pragma unroll
      for (int j = 0; j < 8; ++j) v[j] = (__bf16)src[j];
    } else {
      #pragma unroll
      for (int j = 0; j < 8; ++j) v[j] = (__bf16)0.f;
    }
    *(bf16x8*)&ldsW[((size_t)(nt * KT + kt) * 64 + ll) * 8] = v;
  }
  __syncthreads();

  // ---- hoist the h-part W fragments
  bf16x8 WH[16][2];
  #pragma unroll
  for (int kt = 0; kt < 16; ++kt) {
    WH[kt][0] = *(const bf16x8*)&ldsW[((size_t)(0 * KT + KTx + kt) * 64 + l) * 8];
    WH[kt][1] = *(const bf16x8*)&ldsW[((size_t)(1 * KT + KTx + kt) * 64 + l) * 8];
  }

  // ---- per-lane biases
  float bias0, bias_nx, bias_nh;
  if (c < 8) {
    bias0   = bih[jj] + bhh[jj];
    bias_nx = bih[1024 + jj];
    bias_nh = bhh[1024 + jj];
  } else {
    int j2 = g * 8 + (c - 8);
    bias0   = bih[512 + j2] + bhh[512 + j2];
    bias_nx = 0.f; bias_nh = 0.f;
  }

  floatx4 accA[2], accB[2];
  const floatx4 zero4 = {0.f, 0.f, 0.f, 0.f};
  float hprev[4] = {0.f, 0.f, 0.f, 0.f};

  int* fpost      = fl + ((size_t)((layer * 2 + bg) * 64 + g)) * 32;  // private line
  const int* fown = fl + ((size_t)((layer * 2 + bg) * 64 + l)) * 32;  // own ring
  const int* fx   = fl + ((size_t)(bg * 64 + l)) * 32;                // layer-0 ring

  auto hslab = [&](int t) -> __bf16* {
    return hbase + (size_t)t * (BATCH * HID);
  };

  auto phaseX = [&](int t) {
    accA[0] = zero4; accA[1] = zero4;
    if (layer == 0) {
      const float* xp = x + ((size_t)(rowbase + c) * T_STEPS + t) * 256 + q * 8;
      for (int kt = 0; kt < 8; ++kt) {
        bf16x8 b0 = *(const bf16x8*)&ldsW[((size_t)(0 * KT + kt) * 64 + l) * 8];
        bf16x8 b1 = *(const bf16x8*)&ldsW[((size_t)(1 * KT + kt) * 64 + l) * 8];
        floatx4 u = *(const floatx4*)(xp + kt * 32);
        floatx4 v = *(const floatx4*)(xp + kt * 32 + 4);
        bf16x8 a;
        a[0] = (__bf16)u[0]; a[1] = (__bf16)u[1]; a[2] = (__bf16)u[2]; a[3] = (__bf16)u[3];
        a[4] = (__bf16)v[0]; a[5] = (__bf16)v[1]; a[6] = (__bf16)v[2]; a[7] = (__bf16)v[3];
        accA[0] = __builtin_amdgcn_mfma_f32_16x16x32_bf16(a, b0, accA[0], 0, 0, 0);
        accA[1] = __builtin_amdgcn_mfma_f32_16x16x32_bf16(a, b1, accA[1], 0, 0, 0);
      }
    } else {
      const __bf16* xp = h0base + (size_t)t * (BATCH * HID)
                       + (size_t)(rowbase + c) * HID + q * 8;
      for (int kt = 0; kt < 16; ++kt) {
        bf16x8 b0 = *(const bf16x8*)&ldsW[((size_t)(0 * KT + kt) * 64 + l) * 8];
        bf16x8 b1 = *(const bf16x8*)&ldsW[((size_t)(1 * KT + kt) * 64 + l) * 8];
        bf16x8 a = *(const bf16x8*)(xp + kt * 32);
        accA[0] = __builtin_amdgcn_mfma_f32_16x16x32_bf16(a, b0, accA[0], 0, 0, 0);
        accA[1] = __builtin_amdgcn_mfma_f32_16x16x32_bf16(a, b1, accA[1], 0, 0, 0);
      }
    }
  };

  // ---- prologue
  if (layer == 1) pollline_<2>(fx, 1);
  phaseX(0);

  for (int t = 0; t < T_STEPS; ++t) {
    // ---- phase H: accB = h_{t-1} @ Whh_slice^T (plain cached b128 loads)
    accB[0] = zero4; accB[1] = zero4;
    if (t > 0) {
      const __bf16* hA = hslab(t - 1) + (size_t)(rowbase + c) * HID + q * 8;
      bf16x8 hfrag[16];
      #pragma unroll
      for (int kt = 0; kt < 16; ++kt)
        hfrag[kt] = *(const bf16x8*)(hA + kt * 32);
      #pragma unroll
      for (int kt = 0; kt < 16; ++kt) {
        accB[0] = __builtin_amdgcn_mfma_f32_16x16x32_bf16(hfrag[kt], WH[kt][0], accB[0], 0, 0, 0);
        accB[1] = __builtin_amdgcn_mfma_f32_16x16x32_bf16(hfrag[kt], WH[kt][1], accB[1], 0, 0, 0);
      }
    }

    // ---- epilogue: gates + h update; packed-pair agent stores (write-through)
    __bf16* hs = hslab(t);
    #pragma unroll
    for (int rg = 0; rg < 4; ++rg) {
      float pre0 = accA[0][rg] + accB[0][rg] + bias0;
      float zs = __shfl(pre0, (l & 48) | ((c + 8) & 15), 64);
      float r  = sigmoidf_(pre0);
      float z  = sigmoidf_(zs);
      float nn = tanhf_(accA[1][rg] + bias_nx + r * (accB[1][rg] + bias_nh));
      float hnew = (1.f - z) * nn + z * hprev[rg];
      hprev[rg] = hnew;
      unsigned short us = __builtin_bit_cast(unsigned short, (__bf16)hnew);
      int po = __shfl_xor((int)us, 1, 64);
      if (c < 8 && (c & 1) == 0) {
        uint32_t v = (uint32_t)us | ((uint32_t)po << 16);
        int row = rowbase + q * 4 + rg;
        __hip_atomic_store((uint32_t*)(hs + (size_t)row * HID + jj), v,
                           __ATOMIC_RELAXED, __HIP_MEMORY_SCOPE_AGENT);
      }
    }

    // drain all waves' h stores, then publish step t completion
    asm volatile("s_waitcnt vmcnt(0)" ::: "memory");
    __syncthreads();
    if (tid == 0)
      __hip_atomic_store(fpost, t + 1, __ATOMIC_RELAXED, __HIP_MEMORY_SCOPE_AGENT);

    if (t + 1 < T_STEPS) {
      if (layer == 1) pollline_<2>(fx, t + 2);  // x = h0 slab t+1 ready?
      phaseX(t + 1);                            // hides flag flight / x refill
      pollline_<1>(fown, t + 1);                // peers' h_t visible?
      // no trailing barrier: waves are independent (LDS is read-only here)
    }
  }
}

// yhat[b][o] = h1_last[b][:] . Wout[o][:] + bout[o]
__global__ __launch_bounds__(64) void outproj(const __bf16* __restrict__ h1,
                                              const float* __restrict__ Wout,
                                              const float* __restrict__ bout,
                                              float* __restrict__ out) {
  int b = blockIdx.x, o = threadIdx.x;
  const __bf16* hr = h1 + (size_t)b * HID;
  const float*  wr = Wout + (size_t)o * HID;
  float acc = bout[o];
  for (int k = 0; k < HID; k += 8) {
    bf16x8 h8 = *(const bf16x8*)(hr + k);
    #pragma unroll
    for (int j = 0; j < 8; ++j) acc += (float)h8[j] * wr[k + j];
  }
  out[b * 64 + o] = acc;
}

extern "C" void kernel_launch(void* const* d_in, const int* in_sizes, int n_in,
                              void* d_out, int out_size, void* d_ws, size_t ws_size,
                              hipStream_t stream) {
  const float* x    = (const float*)d_in[0];
  const float* Wih0 = (const float*)d_in[1];
  const float* Whh0 = (const float*)d_in[2];
  const float* bih0 = (const float*)d_in[3];
  const float* bhh0 = (const float*)d_in[4];
  const float* Wih1 = (const float*)d_in[5];
  const float* Whh1 = (const float*)d_in[6];
  const float* bih1 = (const float*)d_in[7];
  const float* bhh1 = (const float*)d_in[8];
  const float* Wout = (const float*)d_in[9];
  const float* bout = (const float*)d_in[10];

  char* ws = (char*)d_ws;
  // ws layout (bytes):
  //   [0, 32 MiB)        h0seq: 256 slabs x 128 KB ([t][b][512] bf16)
  //   [32 MiB, 64 MiB)   h1seq: 256 slabs x 128 KB
  //   [64 MiB, +64 KiB)  flags [2 layer][2 bg][64 g][32 ints] (128B lines)
  __bf16* h0 = (__bf16*)(ws);
  __bf16* h1 = (__bf16*)(ws + (32u << 20));
  int*    fl = (int*)(ws + (64u << 20));

  // zero the flag lines (ws is poisoned before every launch)
  (void)hipMemsetAsync(fl, 0, 2 * 2 * 64 * 32 * 4, stream);

  // fused 2-layer pipelined scan: blocks [0,128) = layer 0, [128,256) = layer 1
  gru_fused<<<256, 256, 0, stream>>>(x,
                                     Wih0, Whh0, bih0, bhh0,
                                     Wih1, Whh1, bih1, bhh1,
                                     h0, h1, fl);

  // final h1 = slab 255
  outproj<<<128, 64, 0, stream>>>(h1 + (size_t)255 * BATCH * HID,
                                  Wout, bout, (float*)d_out);
}